// Round 1
// baseline (78.881 us; speedup 1.0000x reference)
//
#include <hip/hip_runtime.h>

#define KK 3
#define H 512
#define W 512
#define RH 508   // H-K-1
#define RW 508
#define OH 510   // H-K+1
#define OW 510
#define TH 16
#define TW 64
#define XH (TH + 4)   // 20 rows of x needed
#define XW (TW + 4)   // 68 cols of x needed
#define DH (TH + 2)   // 18 rows of dil/ero needed
#define DW (TW + 2)   // 66 cols

__global__ __launch_bounds__(256) void morph2d_fused(
    const float* __restrict__ x,      // (4,512,512)
    const float* __restrict__ w,      // (16,3,3)
    float* __restrict__ out)          // (4,64,510,510)
{
    __shared__ float xs[XH][XW];
    __shared__ float dil_s[DH][DW];
    __shared__ float ero_s[DH][DW];

    const int tid = threadIdx.x;
    const int bg  = blockIdx.y;       // 0..63
    const int b   = bg >> 4;
    const int g   = bg & 15;
    const int tcx = blockIdx.x & 7;   // 8 tiles across (8*64=512 >= 510)
    const int try_ = blockIdx.x >> 3; // 32 tiles down (32*16=512 >= 510)
    const int r0 = try_ * TH;
    const int c0 = tcx * TW;

    // broadcast the 9 binary weights for this group
    float wv[9];
#pragma unroll
    for (int i = 0; i < 9; ++i) wv[i] = w[g * 9 + i];

    // ---- stage 1: x tile -> LDS (guarded at image edge) ----
    const float* xb = x + (size_t)b * (H * W);
    for (int idx = tid; idx < XH * XW; idx += 256) {
        int row = idx / XW, col = idx - row * XW;
        int gr = r0 + row, gc = c0 + col;
        xs[row][col] = (gr < H && gc < W) ? xb[gr * W + gc] : 0.0f;
    }
    __syncthreads();

    // ---- stage 2: dil/ero on haloed region (zero where r>=508 or c>=508,
    //      matching the reference's jnp.pad of the intermediates) ----
    for (int idx = tid; idx < DH * DW; idx += 256) {
        int dr = idx / DW, dc = idx - dr * DW;
        int r = r0 + dr, c = c0 + dc;
        float d = 0.0f, e = 0.0f;
        if (r < RH && c < RW) {
            d = -INFINITY; e = INFINITY;
#pragma unroll
            for (int i = 0; i < KK; ++i)
#pragma unroll
                for (int j = 0; j < KK; ++j) {
                    float xv  = xs[dr + i][dc + j];
                    float wij = wv[i * 3 + j];
                    d = fmaxf(d, fabsf(xv * wij));
                    e = fminf(e, fabsf(xv + wij));
                }
        }
        dil_s[dr][dc] = d;
        ero_s[dr][dc] = e;
    }
    __syncthreads();

    // ---- stage 3: opening/closing + write 4 channels ----
    float* ob = out + ((size_t)b * 64 + (size_t)g * 4) * (size_t)(OH * OW);
    const size_t plane = (size_t)OH * OW;
#pragma unroll
    for (int k = 0; k < 4; ++k) {
        int p = tid + k * 256;          // 16x64 pixels, 4 per thread
        int dr = p >> 6, dc = p & 63;
        int r = r0 + dr, c = c0 + dc;
        if (r >= OH || c >= OW) continue;
        float dv = 0.0f, ev = 0.0f, ov = 0.0f, cv = 0.0f;
        if (r < RH && c < RW) {
            dv = dil_s[dr][dc];
            ev = ero_s[dr][dc];
            ov = -INFINITY; cv = INFINITY;
#pragma unroll
            for (int i = 0; i < KK; ++i)
#pragma unroll
                for (int j = 0; j < KK; ++j) {
                    float es  = ero_s[dr + i][dc + j];
                    float ds  = dil_s[dr + i][dc + j];
                    float wij = wv[i * 3 + j];
                    ov = fmaxf(ov, fabsf(es * wij));
                    cv = fminf(cv, fabsf(ds + wij));
                }
        }
        size_t pix = (size_t)r * OW + c;
        ob[pix]             = dv;   // dilation
        ob[plane + pix]     = ev;   // erosion
        ob[2 * plane + pix] = ov;   // opening
        ob[3 * plane + pix] = cv;   // closing
    }
}

extern "C" void kernel_launch(void* const* d_in, const int* in_sizes, int n_in,
                              void* d_out, int out_size, void* d_ws, size_t ws_size,
                              hipStream_t stream) {
    const float* x = (const float*)d_in[0];   // (4,1,512,512) f32
    const float* w = (const float*)d_in[1];   // (16,1,3,3)  f32
    float* out = (float*)d_out;               // (4,64,510,510) f32
    dim3 grid(8 * 32, 64);   // tiles (8 across x 32 down), 64 (b,g) pairs
    morph2d_fused<<<grid, 256, 0, stream>>>(x, w, out);
}

// Round 2
// 76.680 us; speedup vs baseline: 1.0287x; 1.0287x over previous
//
#include <hip/hip_runtime.h>

#define KK 3
#define H 512
#define W 512
#define RH 508   // H-K-1
#define RW 508
#define OH 510   // H-K+1
#define OW 510
#define TH 16
#define TW 64

// LDS: x tile 20x68 f32; (dil,ero) tile 18x66 float2

__global__ __launch_bounds__(256) void morph2d_fused(
    const float* __restrict__ x,      // (4,512,512)
    const float* __restrict__ w,      // (16,3,3) binary
    float* __restrict__ out)          // (4,64,510,510)
{
    __shared__ float  xs[20][68];
    __shared__ float2 de[18][66];

    const int tid = threadIdx.x;
    const int bg  = blockIdx.y;        // 0..63  (b*16+g)
    const int b   = bg >> 4;
    const int g   = bg & 15;
    const int tcx = blockIdx.x & 7;    // 8 tiles across
    const int tr  = blockIdx.x >> 3;   // 32 tiles down
    const int r0 = tr * TH;
    const int c0 = tcx * TW;

    // ---- uniform weight bitmask (w in {0,1}) ----
    int wm = 0;
#pragma unroll
    for (int t = 0; t < 9; ++t) wm |= (w[g * 9 + t] > 0.5f) ? (1 << t) : 0;
    wm = __builtin_amdgcn_readfirstlane(wm);

    // ---- stage 1: x -> LDS, float2 granularity (20 rows x 34 pairs) ----
    const float* xb = x + (size_t)b * (H * W);
    for (int idx = tid; idx < 20 * 34; idx += 256) {
        int row = idx / 34;
        int s   = idx - row * 34;
        int gr = r0 + row, gc = c0 + 2 * s;
        float2 v = make_float2(0.f, 0.f);
        if (gr < H && gc < W) v = *(const float2*)(xb + gr * W + gc);
        *(float2*)&xs[row][2 * s] = v;
    }
    __syncthreads();

    // ---- stage 2: dil/ero, 18 rows x 11 runs of 6 cols = 198 threads ----
    if (tid < 198) {
        int row = tid / 11;              // 0..17
        int cb  = (tid - row * 11) * 6;  // 0..60
        int gr  = r0 + row;
        float xr[3][8];
#pragma unroll
        for (int i = 0; i < 3; ++i)
#pragma unroll
            for (int q = 0; q < 4; ++q)
                *(float2*)&xr[i][2 * q] = *(const float2*)&xs[row + i][cb + 2 * q];

        float d[6], e[6];
#pragma unroll
        for (int p = 0; p < 6; ++p) { d[p] = 0.f; e[p] = INFINITY; }
#pragma unroll
        for (int T = 0; T < 9; ++T) {
            const int i = T / 3, j = T % 3;
            if (wm & (1 << T)) {
#pragma unroll
                for (int p = 0; p < 6; ++p) {
                    float xv = xr[i][p + j];
                    d[p] = fmaxf(d[p], fabsf(xv));          // |x*1|
                    e[p] = fminf(e[p], fabsf(xv + 1.0f));   // |x+1|
                }
            } else {
#pragma unroll
                for (int p = 0; p < 6; ++p)
                    e[p] = fminf(e[p], fabsf(xr[i][p + j])); // |x+0|
            }
        }
#pragma unroll
        for (int p = 0; p < 6; ++p) {
            bool ok = (gr < RH) && (c0 + cb + p < RW);
            float2 v;
            v.x = ok ? d[p] : 0.f;
            v.y = ok ? e[p] : 0.f;
            de[row][cb + p] = v;
        }
    }
    __syncthreads();

    // ---- stage 3: opening/closing + stores; 16 rows x 16 runs of 4 px ----
    {
        const int rx = tid & 15;
        const int ry = tid >> 4;
        const int cb = 4 * rx;
        const int gr = r0 + ry;

        float2 win[3][6];
#pragma unroll
        for (int i = 0; i < 3; ++i)
#pragma unroll
            for (int j = 0; j < 6; ++j)
                win[i][j] = de[ry + i][cb + j];

        float o[4], m1[4], m0[4];
#pragma unroll
        for (int p = 0; p < 4; ++p) { o[p] = 0.f; m1[p] = INFINITY; m0[p] = INFINITY; }
#pragma unroll
        for (int T = 0; T < 9; ++T) {
            const int i = T / 3, j = T % 3;
            if (wm & (1 << T)) {
#pragma unroll
                for (int p = 0; p < 4; ++p) {
                    o[p]  = fmaxf(o[p],  win[i][p + j].y);   // |ero*1|, ero>=0
                    m1[p] = fminf(m1[p], win[i][p + j].x);   // min dil over w=1
                }
            } else {
#pragma unroll
                for (int p = 0; p < 4; ++p)
                    m0[p] = fminf(m0[p], win[i][p + j].x);   // min dil over w=0
            }
        }

        float dv[4], ev[4], ov[4], cv[4];
#pragma unroll
        for (int p = 0; p < 4; ++p) {
            bool ok = (gr < RH) && (c0 + cb + p < RW);
            dv[p] = ok ? win[0][p].x : 0.f;
            ev[p] = ok ? win[0][p].y : 0.f;
            ov[p] = ok ? o[p] : 0.f;
            cv[p] = ok ? fminf(m1[p] + 1.0f, m0[p]) : 0.f;   // min(dil+w) exact
        }

        if (gr < OH) {
            const size_t plane = (size_t)OH * OW;
            float* ob = out + (size_t)bg * 4 * plane + (size_t)gr * OW;
#pragma unroll
            for (int q = 0; q < 2; ++q) {
                int cc = c0 + cb + 2 * q;
                if (cc < OW) {
                    *(float2*)(ob + cc)             = make_float2(dv[2*q], dv[2*q+1]);
                    *(float2*)(ob + plane + cc)     = make_float2(ev[2*q], ev[2*q+1]);
                    *(float2*)(ob + 2*plane + cc)   = make_float2(ov[2*q], ov[2*q+1]);
                    *(float2*)(ob + 3*plane + cc)   = make_float2(cv[2*q], cv[2*q+1]);
                }
            }
        }
    }
}

extern "C" void kernel_launch(void* const* d_in, const int* in_sizes, int n_in,
                              void* d_out, int out_size, void* d_ws, size_t ws_size,
                              hipStream_t stream) {
    const float* x = (const float*)d_in[0];   // (4,1,512,512) f32
    const float* w = (const float*)d_in[1];   // (16,1,3,3)  f32
    float* out = (float*)d_out;               // (4,64,510,510) f32
    dim3 grid(8 * 32, 64);
    morph2d_fused<<<grid, 256, 0, stream>>>(x, w, out);
}